// Round 15
// baseline (64.852 us; speedup 1.0000x reference)
//
#include <hip/hip_runtime.h>
#include <hip/hip_bf16.h>

#define NN 4096
#define IN_F 128
#define OUT_F 64
#define C_TOT 256
#define ALPHA 0.2f
#define LOG2E 1.4426950408889634f

typedef float f32x4 __attribute__((ext_vector_type(4)));
typedef __bf16 bf16x8 __attribute__((ext_vector_type(8)));

__device__ __forceinline__ unsigned fmap(float f) {
    unsigned u = __float_as_uint(f);
    return (u >> 31) ? ~u : (u | 0x80000000u);
}
__device__ __forceinline__ float funmap(unsigned u) {
    return (u >> 31) ? __uint_as_float(u & 0x7FFFFFFFu) : __uint_as_float(~u);
}
__device__ __forceinline__ unsigned short bfbits(float x) {
    union { __bf16 b; unsigned short u; } t;
    t.b = (__bf16)x;
    return t.u;
}
__device__ __forceinline__ void gl16(const void* g, void* l) {
    __builtin_amdgcn_global_load_lds((const __attribute__((address_space(1))) void*)g,
                                     (__attribute__((address_space(3))) void*)l, 16, 0, 0);
}
__device__ __forceinline__ void gl4(const void* g, void* l) {
    __builtin_amdgcn_global_load_lds((const __attribute__((address_space(1))) void*)g,
                                     (__attribute__((address_space(3))) void*)l, 4, 0, 0);
}

// ---------------------------------------------------------------------------
// K1: adj -> mask2 [rg][jq][t][r64][j4] (tile-contiguous 1KB chunks) via
// ballot; blocks 0..31 transpose W -> WTbf; block 0: uLR=W@a, zero Rmax.
// ---------------------------------------------------------------------------
__global__ __launch_bounds__(256) void k_mask(
    const int* __restrict__ adj, unsigned* __restrict__ mask2,
    const float* __restrict__ W, const float* __restrict__ a,
    unsigned short* __restrict__ WTbf, float* __restrict__ uLR,
    unsigned int* __restrict__ Rmax)
{
    const int tid = threadIdx.x;
    const int lane = tid & 63, wv = tid >> 6;
    const int row = blockIdx.x * 4 + wv;
    const int* __restrict__ ar = adj + (size_t)row * NN;
    const int rg = row >> 6, r64 = row & 63;
    for (int c = 0; c < 8; ++c) {
        const int j0 = c * 512;
        unsigned w = 0u;
#pragma unroll
        for (int k = 0; k < 8; ++k) {
            const unsigned long long bb = __ballot(ar[j0 + k * 64 + lane] > 0);
            const unsigned lo = (unsigned)bb, hi = (unsigned)(bb >> 32);
            if ((lane >> 1) == k) w = (lane & 1) ? hi : lo;
        }
        if (lane < 16) {
            const int wi = c * 16 + lane;              // 0..127
            const int jq = wi >> 5, t = (wi >> 2) & 7, j4 = wi & 3;
            mask2[(size_t)(((rg * 4 + jq) * 8) + t) * 256 + r64 * 4 + j4] = w;
        }
    }

    if (blockIdx.x < 32) {      // merged k_misc
        const int b = blockIdx.x;
        const int c = b * 8 + (tid & 7);
#pragma unroll
        for (int pass = 0; pass < 4; ++pass) {
            const int k = pass * 32 + (tid >> 3);
            WTbf[(size_t)c * IN_F + k] = bfbits(W[k * C_TOT + c]);
        }
        if (b == 0) {
            if (tid < 4) Rmax[tid] = 0u;
            for (int o = tid; o < 1024; o += 256) {
                const int k = o >> 3, j = o & 7;
                const int hd = j & 3, side = j >> 2;
                float s = 0.f;
                for (int f = 0; f < OUT_F; ++f)
                    s = fmaf(W[k * C_TOT + hd * OUT_F + f], a[side * OUT_F + f], s);
                uLR[k * 8 + side * 4 + hd] = s;
            }
        }
    }
}

// ---------------------------------------------------------------------------
// K2: Wh via MFMA -> WhT [256][4096] bf16; f32 left; erPair[hd][j] =
// {exp2(r*log2e), exp2(alpha*r*log2e)}; Rmax atomic.
// ---------------------------------------------------------------------------
__global__ __launch_bounds__(256) void k_prep(
    const float* __restrict__ hmat, const unsigned short* __restrict__ WTbf,
    const float* __restrict__ uLR, unsigned short* __restrict__ WhT,
    float* __restrict__ leftT, float2* __restrict__ erPair,
    unsigned int* __restrict__ Rmax)
{
    __shared__ float hs[16][132];
    __shared__ float us[128][8];
    const int tid = threadIdx.x;
    const int rowbase = blockIdx.x * 16;

    ((float4*)us)[tid] = ((const float4*)uLR)[tid];
#pragma unroll
    for (int p = 0; p < 8; ++p) {
        const int idx = p * 256 + tid;
        hs[idx >> 7][idx & 127] = hmat[(size_t)rowbase * IN_F + idx];
    }
    __syncthreads();

    const int lane = tid & 63, wv = tid >> 6;
    const int m16 = lane & 15, kg = lane >> 4;

    if (wv == 0) {
        const int row = lane >> 2, hd = lane & 3;
        float aL = 0.f, aR = 0.f;
#pragma unroll
        for (int k = 0; k < 128; k += 4) {
            const float4 hv = *(const float4*)&hs[row][k];
            aL = fmaf(hv.x, us[k][hd],   fmaf(hv.y, us[k+1][hd],   fmaf(hv.z, us[k+2][hd],   fmaf(hv.w, us[k+3][hd],   aL))));
            aR = fmaf(hv.x, us[k][hd+4], fmaf(hv.y, us[k+1][hd+4], fmaf(hv.z, us[k+2][hd+4], fmaf(hv.w, us[k+3][hd+4], aR))));
        }
        leftT[hd * NN + rowbase + row] = aL;
        const float rp = aR * LOG2E;
        erPair[(size_t)hd * NN + rowbase + row] = make_float2(exp2f(rp), exp2f(ALPHA * rp));
        float mx = aR;
#pragma unroll
        for (int s = 4; s < 64; s <<= 1) mx = fmaxf(mx, __shfl_xor(mx, s, 64));
        if (lane < 4) atomicMax(&Rmax[hd], fmap(mx));
    }

    bf16x8 afr[4];
#pragma unroll
    for (int ks = 0; ks < 4; ++ks) {
        const float4 lo = *(const float4*)&hs[m16][ks * 32 + kg * 8];
        const float4 hi = *(const float4*)&hs[m16][ks * 32 + kg * 8 + 4];
        bf16x8 v;
        v[0] = (__bf16)lo.x; v[1] = (__bf16)lo.y; v[2] = (__bf16)lo.z; v[3] = (__bf16)lo.w;
        v[4] = (__bf16)hi.x; v[5] = (__bf16)hi.y; v[6] = (__bf16)hi.z; v[7] = (__bf16)hi.w;
        afr[ks] = v;
    }

#pragma unroll
    for (int nt0 = 0; nt0 < 4; ++nt0) {
        const int col = (wv * 4 + nt0) * 16 + m16;
        f32x4 acc = (f32x4){0.f, 0.f, 0.f, 0.f};
#pragma unroll
        for (int ks = 0; ks < 4; ++ks) {
            union { uint4 u; bf16x8 v; } B;
            B.u = *(const uint4*)(WTbf + (size_t)col * IN_F + ks * 32 + kg * 8);
            acc = __builtin_amdgcn_mfma_f32_16x16x32_bf16(afr[ks], B.v, acc, 0, 0, 0);
        }
#pragma unroll
        for (int i = 0; i < 4; ++i)
            WhT[(size_t)col * NN + rowbase + kg * 4 + i] = bfbits(acc[i]);
    }
}

// ---------------------------------------------------------------------------
// K3: attention partials. Grid 1024 x 256: block = 64 rows x 1 head x 1024-j
// quarter; 4 waves = j4 slice. Each wave: 4 row-quarters x 4 col-blocks x its
// 32-j step -> 20 MFMA per 8 LDS reads (0.4 reads/MFMA). Tile (128 j) staged
// as B 16KB + erPair 1KB + mask 1KB via gl16/gl4, 2 buffers, depth-1,
// counted vmcnt(6), 1 barrier/tile. Cross-j4 combine: chunk-major LDS overlay
// (conflict-free b128), 3 serial passes. Partials out; k_fin combines jq.
// ---------------------------------------------------------------------------
__global__ __launch_bounds__(256, 3) void k_attn(
    const unsigned* __restrict__ mask2,
    const unsigned short* __restrict__ WhT,
    const float* __restrict__ leftT,
    const float2* __restrict__ erPair,
    const unsigned int* __restrict__ Rmax,
    float* __restrict__ out,             // jq=0 numerator partial
    float* __restrict__ num123,          // jq=1..3 numerator partials
    float* __restrict__ den)             // [jq][hd][row]
{
    __shared__ unsigned short Bb[2][64 * 128];   // 32KB (comb overlays Bb[0])
    __shared__ float erb[2][256];                // 2KB
    __shared__ unsigned mb[2][256];              // 2KB

    const int tid = threadIdx.x;
    const int lane = tid & 63;
    const int j4 = tid >> 6;        // wave id 0..3
    const int jq = blockIdx.x & 3;
    const int hd = (blockIdx.x >> 2) & 3;
    const int rg = blockIdx.x >> 4;          // 0..63
    const int rowbase = rg * 64;
    const int m = lane & 15;
    const int kg = lane >> 4;
    const int sh = kg * 8;

    // ---- staging geometry ----
    const int srow4 = j4 * 4 + (lane >> 4);      // 0..15 (wave==j4 here)
    const int g_lin = lane & 15;
    const int lg = g_lin ^ srow4;                // inverse-swizzled source granule
    const unsigned short* gB = WhT + (size_t)(hd * 64 + srow4) * NN + jq * 1024 + lg * 8;
    const int dB = srow4 * 128 + g_lin * 8;      // shorts; + p*2048
    const char* gE = (const char*)(erPair + (size_t)hd * NN + jq * 1024);
    const char* gM = (const char*)mask2 + (size_t)((rg * 4 + jq) * 8) * 1024;
    char* eDst = (char*)&erb[0][0];              // + buf*1024 handled below
    char* mDst = (char*)&mb[0][0];

#define STAGE(buf, t) {                                                        \
    gl16(gB + (t) * 128,                      &Bb[buf][dB]);                   \
    gl16(gB + (t) * 128 + (size_t)16 * NN,    &Bb[buf][dB + 2048]);            \
    gl16(gB + (t) * 128 + (size_t)32 * NN,    &Bb[buf][dB + 4096]);            \
    gl16(gB + (t) * 128 + (size_t)48 * NN,    &Bb[buf][dB + 6144]);            \
    gl4(gE + (t) * 1024 + tid * 4, eDst + (buf) * 1024 + j4 * 256 + lane * 4); \
    gl4(gM + (t) * 1024 + tid * 4, mDst + (buf) * 1024 + j4 * 256 + lane * 4); }

    STAGE(0, 0);

    // ---- per-lane constants ----
    const float rmx = funmap(Rmax[hd]);
    float EL[4], EL2[4];
#pragma unroll
    for (int rh = 0; rh < 4; ++rh) {
        const float lf = leftT[hd * NN + rowbase + rh * 16 + m];
        const float x = lf + rmx;
        const float mp0 = fmaxf(x, ALPHA * x) * LOG2E;
        EL [rh] = exp2f(fmaf(lf,         LOG2E, -mp0));
        EL2[rh] = exp2f(fmaf(lf * ALPHA, LOG2E, -mp0));
    }
    bf16x8 ONE8;
#pragma unroll
    for (int i = 0; i < 8; ++i) ONE8[i] = (__bf16)1.0f;

    const int pg8 = ((j4 * 4 + kg) ^ m) * 8;
    const int bro = m * 128 + pg8;               // + q*2048

    f32x4 acc[4][4], accL[4];
#pragma unroll
    for (int rh = 0; rh < 4; ++rh) {
        accL[rh] = (f32x4){0,0,0,0};
#pragma unroll
        for (int q = 0; q < 4; ++q) acc[rh][q] = (f32x4){0,0,0,0};
    }

    __syncthreads();   // drains tile-0 DMA

#define COMPUTE(buf, t) {                                                      \
    unsigned aw[4];                                                            \
    _Pragma("unroll")                                                          \
    for (int rh = 0; rh < 4; ++rh)                                             \
        aw[rh] = mb[buf][(rh * 16 + m) * 4 + j4] >> sh;                        \
    const char* eb = (const char*)&erb[buf][0] + j4 * 256 + kg * 64;           \
    f32x4 V[4];                                                                \
    _Pragma("unroll")                                                          \
    for (int c = 0; c < 4; ++c) V[c] = *(const f32x4*)(eb + c * 16);           \
    union { __bf16 b[8]; bf16x8 v; } Af[4];                                    \
    _Pragma("unroll")                                                          \
    for (int rh = 0; rh < 4; ++rh) {                                           \
        _Pragma("unroll")                                                      \
        for (int c = 0; c < 4; ++c) {                                          \
            float w0 = fmaxf(V[c].x * EL[rh], V[c].y * EL2[rh]);               \
            float w1 = fmaxf(V[c].z * EL[rh], V[c].w * EL2[rh]);               \
            const unsigned mk0 = (unsigned)(((int)(aw[rh] << (31 - 2*c)))     >> 31); \
            const unsigned mk1 = (unsigned)(((int)(aw[rh] << (31 - (2*c+1)))) >> 31); \
            w0 = __uint_as_float(__float_as_uint(w0) & mk0);                   \
            w1 = __uint_as_float(__float_as_uint(w1) & mk1);                   \
            Af[rh].b[2*c]   = (__bf16)w0;                                      \
            Af[rh].b[2*c+1] = (__bf16)w1;                                      \
        }                                                                      \
    }                                                                          \
    union { uint4 u; bf16x8 v; } B[4];                                         \
    _Pragma("unroll")                                                          \
    for (int q = 0; q < 4; ++q) B[q].u = *(const uint4*)&Bb[buf][bro + q*2048];\
    _Pragma("unroll")                                                          \
    for (int rh = 0; rh < 4; ++rh) {                                           \
        _Pragma("unroll")                                                      \
        for (int q = 0; q < 4; ++q)                                            \
            acc[rh][q] = __builtin_amdgcn_mfma_f32_16x16x32_bf16(Af[rh].v, B[q].v, acc[rh][q], 0, 0, 0); \
        accL[rh] = __builtin_amdgcn_mfma_f32_16x16x32_bf16(Af[rh].v, ONE8, accL[rh], 0, 0, 0); \
    }                                                                          \
}

#pragma unroll
    for (int t = 0; t < 8; ++t) {
        if (t < 7) {
            STAGE((t + 1) & 1, t + 1);
            asm volatile("s_waitcnt vmcnt(6)" ::: "memory");   // tile t landed
        } else {
            asm volatile("s_waitcnt vmcnt(0)" ::: "memory");
        }
        __builtin_amdgcn_sched_barrier(0);
        COMPUTE(t & 1, t);
        __builtin_amdgcn_sched_barrier(0);
        __builtin_amdgcn_s_barrier();
    }
#undef STAGE
#undef COMPUTE

    // ---- cross-j4 combine: chunk-major [20][64][4] overlay (conflict-free) ----
    __syncthreads();
    float* comb = (float*)&Bb[0][0];
#pragma unroll
    for (int p = 1; p < 4; ++p) {
        if (j4 == p) {
#pragma unroll
            for (int rh = 0; rh < 4; ++rh) {
#pragma unroll
                for (int q = 0; q < 4; ++q)
                    *(f32x4*)&comb[((rh * 4 + q) * 64 + lane) * 4] = acc[rh][q];
                *(f32x4*)&comb[((16 + rh) * 64 + lane) * 4] = accL[rh];
            }
        }
        __syncthreads();
        if (j4 == 0) {
#pragma unroll
            for (int rh = 0; rh < 4; ++rh) {
#pragma unroll
                for (int q = 0; q < 4; ++q)
                    acc[rh][q] += *(const f32x4*)&comb[((rh * 4 + q) * 64 + lane) * 4];
                accL[rh] += *(const f32x4*)&comb[((16 + rh) * 64 + lane) * 4];
            }
        }
        __syncthreads();
    }

    if (j4 == 0) {
        float* numdst = (jq == 0) ? out : (num123 + (size_t)(jq - 1) * NN * C_TOT);
#pragma unroll
        for (int rh = 0; rh < 4; ++rh) {
#pragma unroll
            for (int q = 0; q < 4; ++q) {
                const int col = hd * 64 + q * 16 + m;
#pragma unroll
                for (int i = 0; i < 4; ++i)
                    numdst[(size_t)(rowbase + rh * 16 + kg * 4 + i) * C_TOT + col] = acc[rh][q][i];
            }
        }
        if (m == 0) {
#pragma unroll
            for (int rh = 0; rh < 4; ++rh)
#pragma unroll
                for (int i = 0; i < 4; ++i)
                    den[(size_t)(jq * 4 + hd) * NN + rowbase + rh * 16 + kg * 4 + i] = accL[rh][i];
        }
    }
}

// ---------------------------------------------------------------------------
// K4: finalize — out = (sum of 4 jq numerators) / (sum of 4 jq denoms) + bias.
// ---------------------------------------------------------------------------
__global__ __launch_bounds__(256) void k_fin(
    float* __restrict__ out, const float* __restrict__ num123,
    const float* __restrict__ den, const float* __restrict__ bias)
{
    const int idx = blockIdx.x * 256 + threadIdx.x;   // float4 index
    const int row = idx >> 6;
    const int c4 = (idx & 63) * 4;
    const int hd = c4 >> 6;
    const float d = den[(0 * 4 + hd) * NN + row] + den[(1 * 4 + hd) * NN + row]
                  + den[(2 * 4 + hd) * NN + row] + den[(3 * 4 + hd) * NN + row];
    const float rd = 1.0f / d;
    const size_t off = (size_t)row * C_TOT + c4;
    float4 n = *(float4*)(out + off);
    const float4 n1 = *(const float4*)(num123 + off);
    const float4 n2 = *(const float4*)(num123 + (size_t)NN * C_TOT + off);
    const float4 n3 = *(const float4*)(num123 + (size_t)2 * NN * C_TOT + off);
    const float4 bv = *(const float4*)(bias + c4);
    n.x = fmaf(n.x + n1.x + n2.x + n3.x, rd, bv.x);
    n.y = fmaf(n.y + n1.y + n2.y + n3.y, rd, bv.y);
    n.z = fmaf(n.z + n1.z + n2.z + n3.z, rd, bv.z);
    n.w = fmaf(n.w + n1.w + n2.w + n3.w, rd, bv.w);
    *(float4*)(out + off) = n;
}

extern "C" void kernel_launch(void* const* d_in, const int* in_sizes, int n_in,
                              void* d_out, int out_size, void* d_ws, size_t ws_size,
                              hipStream_t stream) {
    const float* hmat = (const float*)d_in[0];
    const int*   adj  = (const int*)d_in[1];
    const float* W    = (const float*)d_in[2];
    const float* a    = (const float*)d_in[3];
    const float* bias = (const float*)d_in[4];
    float* out = (float*)d_out;

    char* ws = (char*)d_ws;
    unsigned short* WhT  = (unsigned short*)(ws + 0x000000);   // 2MB + pad
    float* leftT         = (float*)(ws + 0x2A0000);            // 64KB
    unsigned short* WTbf = (unsigned short*)(ws + 0x2B0000);   // 64KB
    float* uLR           = (float*)(ws + 0x2C0000);            // 4KB
    unsigned int* Rmax   = (unsigned int*)(ws + 0x2C1000);     // 16B
    float2* erPair       = (float2*)(ws + 0x2C2000);           // 128KB
    unsigned* mask2      = (unsigned*)(ws + 0x300000);         // 2MB
    float* num123        = (float*)(ws + 0x500000);            // 12MB
    float* den           = (float*)(ws + 0x1100000);           // 256KB

    hipLaunchKernelGGL(k_mask, dim3(1024), dim3(256), 0, stream,
                       adj, mask2, W, a, WTbf, uLR, Rmax);
    hipLaunchKernelGGL(k_prep, dim3(256),  dim3(256), 0, stream,
                       hmat, WTbf, uLR, WhT, leftT, erPair, Rmax);
    hipLaunchKernelGGL(k_attn, dim3(1024), dim3(256), 0, stream,
                       mask2, WhT, leftT, erPair, Rmax, out, num123, den);
    hipLaunchKernelGGL(k_fin,  dim3(1024), dim3(256), 0, stream,
                       out, num123, den, bias);
}